// Round 6
// baseline (232.668 us; speedup 1.0000x reference)
//
#include <hip/hip_runtime.h>
#include <math.h>

#define BB 2
#define DD 8
#define NN 40
#define HH 128
#define HID 512
#define NJK 1600            // NN*NN
#define MROW 64000          // NN*NJK rows per batch

typedef __attribute__((ext_vector_type(8))) short short8;
typedef __attribute__((ext_vector_type(4))) float floatx4;

static __device__ __forceinline__ unsigned short f2bf(float x) {
    unsigned int b = __float_as_uint(x);
    b += 0x7fffu + ((b >> 16) & 1u);
    return (unsigned short)(b >> 16);
}

static __device__ __forceinline__ void gload_lds16(const void* g, void* l) {
    __builtin_amdgcn_global_load_lds(
        (const __attribute__((address_space(1))) unsigned int*)g,
        (__attribute__((address_space(3))) unsigned int*)l, 16, 0, 0);
}

// ---------------- prep: hp, hnb, w2f (unchanged from R5) ----------------
__global__ __launch_bounds__(256) void prep_kernel(
        const float* __restrict__ node, const float* __restrict__ pair,
        const float* __restrict__ W1n, const float* __restrict__ W1p,
        const float* __restrict__ b1, const float* __restrict__ W2,
        float* __restrict__ hp, float* __restrict__ hnb,
        unsigned short* __restrict__ w2f) {
    __shared__ float smem[32 * 513];
    const int bid = blockIdx.x;
    const int t = threadIdx.x;

    if (bid < 400) {                                   // ---- hp ----
        float (*pf)[HH] = (float (*)[HH])smem;
        const int rowbase = bid * 8;
        #pragma unroll
        for (int e = t; e < 8*HH; e += 256) {
            int r8 = e >> 7, c = e & 127;
            int grow = rowbase + r8;
            int b = grow / NJK, jk = grow - b*NJK;
            float m = -INFINITY;
            #pragma unroll
            for (int d = 0; d < DD; ++d)
                m = fmaxf(m, pair[((size_t)((b*DD + d)*NJK + jk))*HH + c]);
            pf[r8][c] = m;
        }
        __syncthreads();
        const int rg = t >> 7, c4 = (t & 127) * 4;
        float4 acc[4];
        #pragma unroll
        for (int r = 0; r < 4; ++r) acc[r] = make_float4(0.f,0.f,0.f,0.f);
        #pragma unroll 4
        for (int h = 0; h < HH; ++h) {
            float4 wv = *(const float4*)&W1p[h*HID + c4];
            #pragma unroll
            for (int r = 0; r < 4; ++r) {
                float pv = pf[rg*4 + r][h];
                acc[r].x = fmaf(pv, wv.x, acc[r].x);
                acc[r].y = fmaf(pv, wv.y, acc[r].y);
                acc[r].z = fmaf(pv, wv.z, acc[r].z);
                acc[r].w = fmaf(pv, wv.w, acc[r].w);
            }
        }
        #pragma unroll
        for (int r = 0; r < 4; ++r)
            *(float4*)&hp[(size_t)(rowbase + rg*4 + r)*HID + c4] = acc[r];
    } else if (bid < 410) {                            // ---- hnb ----
        float (*nf)[HH] = (float (*)[HH])smem;
        const int rowbase = (bid - 400) * 8;
        #pragma unroll
        for (int e = t; e < 8*HH; e += 256) {
            int r8 = e >> 7, c = e & 127;
            int grow = rowbase + r8;
            int b = grow / NN, i = grow - b*NN;
            float m = -INFINITY;
            #pragma unroll
            for (int d = 0; d < DD; ++d)
                m = fmaxf(m, node[((size_t)((b*DD + d)*NN + i))*HH + c]);
            nf[r8][c] = m;
        }
        __syncthreads();
        const int rg = t >> 7, c4 = (t & 127) * 4;
        float4 acc[4];
        #pragma unroll
        for (int r = 0; r < 4; ++r) acc[r] = make_float4(0.f,0.f,0.f,0.f);
        #pragma unroll 4
        for (int h = 0; h < HH; ++h) {
            float4 wv = *(const float4*)&W1n[h*HID + c4];
            #pragma unroll
            for (int r = 0; r < 4; ++r) {
                float nv = nf[rg*4 + r][h];
                acc[r].x = fmaf(nv, wv.x, acc[r].x);
                acc[r].y = fmaf(nv, wv.y, acc[r].y);
                acc[r].z = fmaf(nv, wv.z, acc[r].z);
                acc[r].w = fmaf(nv, wv.w, acc[r].w);
            }
        }
        float4 b1v = *(const float4*)&b1[c4];
        #pragma unroll
        for (int r = 0; r < 4; ++r) {
            float4 o = make_float4(acc[r].x + b1v.x, acc[r].y + b1v.y,
                                   acc[r].z + b1v.z, acc[r].w + b1v.w);
            *(float4*)&hnb[(size_t)(rowbase + rg*4 + r)*HID + c4] = o;
        }
    } else {                                           // ---- w2f ----
        const int ks = bid - 410;
        for (int e = t; e < 32*HID; e += 256) {
            int r = e >> 9, c = e & 511;
            smem[r*513 + c] = W2[(size_t)(ks*32 + r)*HID + c];
        }
        __syncthreads();
        const int w = t >> 6, l = t & 63;
        const int lr = l & 15, lg = l >> 4;
        #pragma unroll
        for (int f = 0; f < 8; ++f) {
            int cf = w*8 + f;
            short8 u;
            #pragma unroll
            for (int kk = 0; kk < 8; ++kk)
                u[kk] = (short)f2bf(smem[(lg*8 + kk)*513 + cf*16 + lr]);
            *(short8*)(w2f + (size_t)(cf*16 + ks)*512 + l*8) = u;
        }
    }
}

// ---------------- prep2: h1f = relu(hnb+hp) bf16 in MFMA-fragment order ----
// h1f[p][ks][mi][lane][8]: block p covers rows p*128..+127;
// slot (ks,mi,l,e) <-> row = p*128 + mi*16 + (l&15), k = ks*32 + (l>>4)*8 + e
__global__ __launch_bounds__(256) void prep2_kernel(
        const float* __restrict__ hp, const float* __restrict__ hnb,
        unsigned short* __restrict__ h1f) {
    const int p = blockIdx.x;          // 0..999
    const int t = threadIdx.x;
    #pragma unroll 4
    for (int j = 0; j < 32; ++j) {
        int s  = j*256 + t;            // 0..8191
        int ks = s >> 9, mi = (s >> 6) & 7, l = s & 63;
        int grow = p*128 + mi*16 + (l & 15);
        int b  = grow / MROW;
        int r  = grow - b*MROW;
        int i  = r / NJK;
        int jk = r - i*NJK;
        int k0 = ks*32 + (l >> 4)*8;
        const float* hr = hp  + ((size_t)b*NJK + jk)*HID + k0;
        const float* nr = hnb + ((size_t)(b*NN + i))*HID + k0;
        float4 p0 = *(const float4*)hr, p1 = *(const float4*)(hr + 4);
        float4 n0 = *(const float4*)nr, n1 = *(const float4*)(nr + 4);
        short8 u;
        u[0] = (short)f2bf(fmaxf(p0.x + n0.x, 0.f));
        u[1] = (short)f2bf(fmaxf(p0.y + n0.y, 0.f));
        u[2] = (short)f2bf(fmaxf(p0.z + n0.z, 0.f));
        u[3] = (short)f2bf(fmaxf(p0.w + n0.w, 0.f));
        u[4] = (short)f2bf(fmaxf(p1.x + n1.x, 0.f));
        u[5] = (short)f2bf(fmaxf(p1.y + n1.y, 0.f));
        u[6] = (short)f2bf(fmaxf(p1.z + n1.z, 0.f));
        u[7] = (short)f2bf(fmaxf(p1.w + n1.w, 0.f));
        *(short8*)(h1f + (size_t)p*65536 + (size_t)s*8) = u;
    }
}

// ---------------- main2: pure GEMM from fragment-packed h1f ----------------
// 1000 blocks x 512. 8 waves, wave w = all 128 rows x cols [w*64,(w+1)*64).
// A: 3-deep global_load_lds slice pipeline (8KB/ks), counted vmcnt, raw barrier.
// B: 1-ahead register prefetch from w2f (L2). Zero LDS bank conflicts.
__global__ __launch_bounds__(512, 2) void main2_kernel(
        const unsigned short* __restrict__ h1f,
        const unsigned short* __restrict__ w2f,
        const float* __restrict__ b2, const float* __restrict__ W3,
        const float* __restrict__ b3, const float* __restrict__ scale,
        const float* __restrict__ bias, float* __restrict__ out) {
    __shared__ __align__(16) unsigned short asl[3 * 4096];   // 3 x 8KB slices
    __shared__ float red[8][128];

    const int p = blockIdx.x;          // 0..999
    const int t = threadIdx.x;
    const int w = t >> 6, l = t & 63;
    const int lr = l & 15, lg = l >> 4;

    const unsigned short* ablk = h1f + (size_t)p*65536;
    // wave w stages frag mi=w of each slice: global per-lane, LDS base uniform
    #define ISSUE_A(ks, buf) \
        gload_lds16(ablk + (ks)*4096 + w*512 + l*8, &asl[(buf)*4096 + w*512])

    floatx4 acc[8][4];
    #pragma unroll
    for (int mi = 0; mi < 8; ++mi)
        #pragma unroll
        for (int tn = 0; tn < 4; ++tn)
            acc[mi][tn] = (floatx4){0.f, 0.f, 0.f, 0.f};

    const unsigned short* bbase = w2f + (size_t)w*32768 + l*8;

    ISSUE_A(0, 0);
    ISSUE_A(1, 1);
    short8 bcur[4];
    #pragma unroll
    for (int tn = 0; tn < 4; ++tn)
        bcur[tn] = *(const short8*)(bbase + ((tn*16) << 9));

    #pragma unroll 1
    for (int ks = 0; ks < 16; ++ks) {
        __builtin_amdgcn_s_barrier();          // all waves done reading ks-1
        if (ks < 14) {
            int buf = (ks + 2) % 3;
            ISSUE_A(ks + 2, buf);
        }
        short8 bnxt[4];
        int ksn = (ks + 1) & 15;
        #pragma unroll
        for (int tn = 0; tn < 4; ++tn)
            bnxt[tn] = *(const short8*)(bbase + ((tn*16 + ksn) << 9));
        // slice ks DMA is >=6 issues old in every wave -> vmcnt(5) covers it
        asm volatile("s_waitcnt vmcnt(5)" ::: "memory");
        __builtin_amdgcn_sched_barrier(0);

        const unsigned short* sl = asl + (ks % 3) * 4096;
        #pragma unroll
        for (int mi = 0; mi < 8; ++mi) {
            short8 a = *(const short8*)(sl + mi*512 + l*8);
            #pragma unroll
            for (int tn = 0; tn < 4; ++tn)
                acc[mi][tn] = __builtin_amdgcn_mfma_f32_16x16x32_bf16(a, bcur[tn], acc[mi][tn], 0, 0, 0);
        }
        #pragma unroll
        for (int tn = 0; tn < 4; ++tn) bcur[tn] = bnxt[tn];
    }
    #undef ISSUE_A

    // epilogue: v = relu(acc+b2)@W3, reduce over col-waves, sigmoid
    float b2v[4], w3v[4];
    #pragma unroll
    for (int tn = 0; tn < 4; ++tn) {
        int col = w*64 + tn*16 + lr;
        b2v[tn] = b2[col];
        w3v[tn] = W3[col];
    }
    #pragma unroll
    for (int mi = 0; mi < 8; ++mi) {
        #pragma unroll
        for (int q = 0; q < 4; ++q) {
            float s = 0.f;
            #pragma unroll
            for (int tn = 0; tn < 4; ++tn)
                s += fmaxf(acc[mi][tn][q] + b2v[tn], 0.f) * w3v[tn];
            s += __shfl_xor(s, 1);
            s += __shfl_xor(s, 2);
            s += __shfl_xor(s, 4);
            s += __shfl_xor(s, 8);
            if (lr == 0) red[w][mi*16 + lg*4 + q] = s;
        }
    }
    __syncthreads();
    if (t < 128) {
        float v = b3[0];
        #pragma unroll
        for (int c = 0; c < 8; ++c) v += red[c][t];
        float z = scale[0]*v + bias[0];
        out[(size_t)p*128 + t] = 1.0f / (1.0f + expf(-z));
    }
}

// ---------------- fallback fused main (R5, known-good) ----------------
__global__ __launch_bounds__(512, 2) void main_kernel(
        const float* __restrict__ hp, const float* __restrict__ hnb,
        const unsigned short* __restrict__ w2f,
        const float* __restrict__ b2, const float* __restrict__ W3,
        const float* __restrict__ b3, const float* __restrict__ scale,
        const float* __restrict__ bias, float* __restrict__ out) {
    __shared__ unsigned short h1s[128 * HID];
    __shared__ float red[8][128];

    const int bid  = blockIdx.x;
    const int bid8 = (bid & 7)*125 + (bid >> 3);
    const int b    = bid8 / 500;
    const int rr_  = bid8 % 500;
    const int i0   = (rr_ / 100) * 8;
    const int jk0  = (rr_ % 100) * 16;
    const int t    = threadIdx.x;
    char* h1c = (char*)h1s;

    const float* hpb  = hp  + ((size_t)b*NJK + jk0)*HID;
    const float* hnbb = hnb + ((size_t)(b*NN + i0))*HID;
    #pragma unroll 4
    for (int it = 0; it < 16; ++it) {
        int g   = it*512 + t;
        int row = g >> 6, k8 = g & 63;
        int il  = row >> 4, jl = row & 15;
        const float* hr = hpb  + (size_t)jl*HID + k8*8;
        const float* nr = hnbb + (size_t)il*HID + k8*8;
        float4 p0 = *(const float4*)hr, p1 = *(const float4*)(hr + 4);
        float4 n0 = *(const float4*)nr, n1 = *(const float4*)(nr + 4);
        short8 u;
        u[0] = (short)f2bf(fmaxf(p0.x + n0.x, 0.f));
        u[1] = (short)f2bf(fmaxf(p0.y + n0.y, 0.f));
        u[2] = (short)f2bf(fmaxf(p0.z + n0.z, 0.f));
        u[3] = (short)f2bf(fmaxf(p0.w + n0.w, 0.f));
        u[4] = (short)f2bf(fmaxf(p1.x + n1.x, 0.f));
        u[5] = (short)f2bf(fmaxf(p1.y + n1.y, 0.f));
        u[6] = (short)f2bf(fmaxf(p1.z + n1.z, 0.f));
        u[7] = (short)f2bf(fmaxf(p1.w + n1.w, 0.f));
        int off = ((row << 10) + (k8 << 4)) ^ ((row & 7) << 4);
        *(short8*)(h1c + off) = u;
    }
    __syncthreads();

    const int w  = t >> 6, l = t & 63;
    const int lr = l & 15, lg = l >> 4;
    const int swz = (lr & 7) << 4;

    floatx4 acc[8][4];
    #pragma unroll
    for (int mi = 0; mi < 8; ++mi)
        #pragma unroll
        for (int tn = 0; tn < 4; ++tn)
            acc[mi][tn] = (floatx4){0.f, 0.f, 0.f, 0.f};

    const unsigned short* bbase = w2f + (size_t)w*32768 + l*8;

    short8 bcur[4];
    #pragma unroll
    for (int tn = 0; tn < 4; ++tn)
        bcur[tn] = *(const short8*)(bbase + ((tn*16 + 0) << 9));

    #pragma unroll 1
    for (int ks = 0; ks < 16; ++ks) {
        short8 bnxt[4];
        int ksn = (ks + 1) & 15;
        #pragma unroll
        for (int tn = 0; tn < 4; ++tn)
            bnxt[tn] = *(const short8*)(bbase + ((tn*16 + ksn) << 9));
        short8 av[8];
        #pragma unroll
        for (int mi = 0; mi < 8; ++mi) {
            int aoff = (((mi*16 + lr) << 10) + (ks << 6) + (lg << 4)) ^ swz;
            av[mi] = *(const short8*)(h1c + aoff);
        }
        #pragma unroll
        for (int mi = 0; mi < 8; ++mi)
            #pragma unroll
            for (int tn = 0; tn < 4; ++tn)
                acc[mi][tn] = __builtin_amdgcn_mfma_f32_16x16x32_bf16(av[mi], bcur[tn], acc[mi][tn], 0, 0, 0);
        #pragma unroll
        for (int tn = 0; tn < 4; ++tn) bcur[tn] = bnxt[tn];
    }

    float b2v[4], w3v[4];
    #pragma unroll
    for (int tn = 0; tn < 4; ++tn) {
        int col = w*64 + tn*16 + lr;
        b2v[tn] = b2[col];
        w3v[tn] = W3[col];
    }
    #pragma unroll
    for (int mi = 0; mi < 8; ++mi) {
        #pragma unroll
        for (int q = 0; q < 4; ++q) {
            float s = 0.f;
            #pragma unroll
            for (int tn = 0; tn < 4; ++tn)
                s += fmaxf(acc[mi][tn][q] + b2v[tn], 0.f) * w3v[tn];
            s += __shfl_xor(s, 1);
            s += __shfl_xor(s, 2);
            s += __shfl_xor(s, 4);
            s += __shfl_xor(s, 8);
            if (lr == 0) red[w][mi*16 + lg*4 + q] = s;
        }
    }
    __syncthreads();
    if (t < 128) {
        float v = b3[0];
        #pragma unroll
        for (int c = 0; c < 8; ++c) v += red[c][t];
        float z = scale[0]*v + bias[0];
        int il = t >> 4, jl = t & 15;
        out[(size_t)b*MROW + (size_t)(i0 + il)*NJK + jk0 + jl] =
            1.0f / (1.0f + expf(-z));
    }
}

extern "C" void kernel_launch(void* const* d_in, const int* in_sizes, int n_in,
                              void* d_out, int out_size, void* d_ws, size_t ws_size,
                              hipStream_t stream) {
    const float* node  = (const float*)d_in[0];
    const float* pair  = (const float*)d_in[1];
    const float* W1n   = (const float*)d_in[2];
    const float* W1p   = (const float*)d_in[3];
    const float* b1    = (const float*)d_in[4];
    const float* W2    = (const float*)d_in[5];
    const float* b2    = (const float*)d_in[6];
    const float* W3    = (const float*)d_in[7];
    const float* b3    = (const float*)d_in[8];
    const float* scale = (const float*)d_in[9];
    const float* bias  = (const float*)d_in[10];
    float* out = (float*)d_out;

    float* hp  = (float*)d_ws;                                  // 6,553,600 B
    float* hnb = hp + (size_t)BB*NJK*HID;                       //   163,840 B
    unsigned short* w2f = (unsigned short*)(hnb + BB*NN*HID);   //   524,288 B
    unsigned short* h1f = w2f + 262144;                         // 131,072,000 B

    const size_t need = 6553600ull + 163840ull + 524288ull + 131072000ull;

    hipLaunchKernelGGL(prep_kernel, dim3(426), dim3(256), 0, stream,
                       node, pair, W1n, W1p, b1, W2, hp, hnb, w2f);
    if (ws_size >= need) {
        hipLaunchKernelGGL(prep2_kernel, dim3(1000), dim3(256), 0, stream,
                           hp, hnb, h1f);
        hipLaunchKernelGGL(main2_kernel, dim3(1000), dim3(512), 0, stream,
                           h1f, w2f, b2, W3, b3, scale, bias, out);
    } else {
        hipLaunchKernelGGL(main_kernel, dim3(1000), dim3(512), 0, stream,
                           hp, hnb, w2f, b2, W3, b3, scale, bias, out);
    }
}

// Round 7
// 199.973 us; speedup vs baseline: 1.1635x; 1.1635x over previous
//
#include <hip/hip_runtime.h>
#include <math.h>

#define BB 2
#define DD 8
#define NN 40
#define HH 128
#define HID 512
#define NJK 1600            // NN*NN
#define MROW 64000          // NN*NJK rows per batch

typedef __attribute__((ext_vector_type(8))) short short8;
typedef __attribute__((ext_vector_type(4))) float floatx4;

static __device__ __forceinline__ unsigned short f2bf(float x) {
    unsigned int b = __float_as_uint(x);
    b += 0x7fffu + ((b >> 16) & 1u);
    return (unsigned short)(b >> 16);
}

// Fused prep, 426 blocks x 256 (R5 structure, known-good):
//  bid [0,400)   : hp rows bid*8..+7      (max_d(pair) @ W1p, fp32)
//  bid [400,410) : hnb rows (bid-400)*8..+7  (max_d(node) @ W1n + b1)
//  bid [410,426) : w2f — W2 k-slice ks=bid-410 packed bf16 in MFMA-frag order:
//                  frag f = cf*16+ks at w2f+f*512; lane l: n=cf*16+(l&15),
//                  k = ks*32+(l>>4)*8 .. +7
__global__ __launch_bounds__(256) void prep_kernel(
        const float* __restrict__ node, const float* __restrict__ pair,
        const float* __restrict__ W1n, const float* __restrict__ W1p,
        const float* __restrict__ b1, const float* __restrict__ W2,
        float* __restrict__ hp, float* __restrict__ hnb,
        unsigned short* __restrict__ w2f) {
    __shared__ float smem[32 * 513];
    const int bid = blockIdx.x;
    const int t = threadIdx.x;

    if (bid < 400) {                                   // ---- hp ----
        float (*pf)[HH] = (float (*)[HH])smem;
        const int rowbase = bid * 8;
        #pragma unroll
        for (int e = t; e < 8*HH; e += 256) {
            int r8 = e >> 7, c = e & 127;
            int grow = rowbase + r8;
            int b = grow / NJK, jk = grow - b*NJK;
            float m = -INFINITY;
            #pragma unroll
            for (int d = 0; d < DD; ++d)
                m = fmaxf(m, pair[((size_t)((b*DD + d)*NJK + jk))*HH + c]);
            pf[r8][c] = m;
        }
        __syncthreads();
        const int rg = t >> 7, c4 = (t & 127) * 4;
        float4 acc[4];
        #pragma unroll
        for (int r = 0; r < 4; ++r) acc[r] = make_float4(0.f,0.f,0.f,0.f);
        #pragma unroll 4
        for (int h = 0; h < HH; ++h) {
            float4 wv = *(const float4*)&W1p[h*HID + c4];
            #pragma unroll
            for (int r = 0; r < 4; ++r) {
                float pv = pf[rg*4 + r][h];
                acc[r].x = fmaf(pv, wv.x, acc[r].x);
                acc[r].y = fmaf(pv, wv.y, acc[r].y);
                acc[r].z = fmaf(pv, wv.z, acc[r].z);
                acc[r].w = fmaf(pv, wv.w, acc[r].w);
            }
        }
        #pragma unroll
        for (int r = 0; r < 4; ++r)
            *(float4*)&hp[(size_t)(rowbase + rg*4 + r)*HID + c4] = acc[r];
    } else if (bid < 410) {                            // ---- hnb ----
        float (*nf)[HH] = (float (*)[HH])smem;
        const int rowbase = (bid - 400) * 8;
        #pragma unroll
        for (int e = t; e < 8*HH; e += 256) {
            int r8 = e >> 7, c = e & 127;
            int grow = rowbase + r8;
            int b = grow / NN, i = grow - b*NN;
            float m = -INFINITY;
            #pragma unroll
            for (int d = 0; d < DD; ++d)
                m = fmaxf(m, node[((size_t)((b*DD + d)*NN + i))*HH + c]);
            nf[r8][c] = m;
        }
        __syncthreads();
        const int rg = t >> 7, c4 = (t & 127) * 4;
        float4 acc[4];
        #pragma unroll
        for (int r = 0; r < 4; ++r) acc[r] = make_float4(0.f,0.f,0.f,0.f);
        #pragma unroll 4
        for (int h = 0; h < HH; ++h) {
            float4 wv = *(const float4*)&W1n[h*HID + c4];
            #pragma unroll
            for (int r = 0; r < 4; ++r) {
                float nv = nf[rg*4 + r][h];
                acc[r].x = fmaf(nv, wv.x, acc[r].x);
                acc[r].y = fmaf(nv, wv.y, acc[r].y);
                acc[r].z = fmaf(nv, wv.z, acc[r].z);
                acc[r].w = fmaf(nv, wv.w, acc[r].w);
            }
        }
        float4 b1v = *(const float4*)&b1[c4];
        #pragma unroll
        for (int r = 0; r < 4; ++r) {
            float4 o = make_float4(acc[r].x + b1v.x, acc[r].y + b1v.y,
                                   acc[r].z + b1v.z, acc[r].w + b1v.w);
            *(float4*)&hnb[(size_t)(rowbase + rg*4 + r)*HID + c4] = o;
        }
    } else {                                           // ---- w2f ----
        const int ks = bid - 410;
        for (int e = t; e < 32*HID; e += 256) {
            int r = e >> 9, c = e & 511;
            smem[r*513 + c] = W2[(size_t)(ks*32 + r)*HID + c];
        }
        __syncthreads();
        const int w = t >> 6, l = t & 63;
        const int lr = l & 15, lg = l >> 4;
        #pragma unroll
        for (int f = 0; f < 8; ++f) {
            int cf = w*8 + f;
            short8 u;
            #pragma unroll
            for (int kk = 0; kk < 8; ++kk)
                u[kk] = (short)f2bf(smem[(lg*8 + kk)*513 + cf*16 + lr]);
            *(short8*)(w2f + (size_t)(cf*16 + ks)*512 + l*8) = u;
        }
    }
}

// Main: 1000 blocks x 512. Tile = 8 i x 16 jk = 128 rows x 512 cols.
// h1 staged in LDS in MFMA-FRAGMENT-PACKED layout: frag (ks,mi) = contiguous
// 1KB at (ks*8+mi)*1024; lane l holds row mi*16+(l&15), k ks*32+(l>>4)*8..+7.
// -> stage writes: 1 contiguous 1KB per wave per slice (0 conflicts)
// -> k-loop A-reads: lane-stride-1 ds_read_b128 (0 conflicts, no swizzle)
// 8 waves, wave w = all 128 rows x cols [w*64,(w+1)*64): acc[8][4];
// B 1-ahead register prefetch from fragment-packed w2f (L2). No k-loop barriers.
__global__ __launch_bounds__(512, 2) void main_kernel(
        const float* __restrict__ hp, const float* __restrict__ hnb,
        const unsigned short* __restrict__ w2f,
        const float* __restrict__ b2, const float* __restrict__ W3,
        const float* __restrict__ b3, const float* __restrict__ scale,
        const float* __restrict__ bias, float* __restrict__ out) {
    __shared__ __align__(16) unsigned short h1s[128 * HID];  // 128 KiB frag-packed
    __shared__ float red[8][128];                            // 4 KiB

    const int bid  = blockIdx.x;                       // 0..999
    const int bid8 = (bid & 7)*125 + (bid >> 3);       // bijective XCD swizzle
    const int b    = bid8 / 500;
    const int rr_  = bid8 % 500;
    const int i0   = (rr_ / 100) * 8;
    const int jk0  = (rr_ % 100) * 16;
    const int t    = threadIdx.x;
    char* h1c = (char*)h1s;

    const int w  = t >> 6, l = t & 63;                 // wave id == mi for stage
    const int lr = l & 15, lg = l >> 4;

    // hoist first B-frag loads (independent of LDS) to overlap the stage
    const unsigned short* bbase = w2f + (size_t)w*32768 + l*8;
    short8 bcur[4];
    #pragma unroll
    for (int tn = 0; tn < 4; ++tn)
        bcur[tn] = *(const short8*)(bbase + ((tn*16) << 9));

    // ---- stage h1 = relu(hnb[i0+mi] + hp[jk0+lr]) into frag-packed LDS ----
    // wave w handles frag rows il=w; lane reads hp row jl=lr (16x128B segments
    // per wave, L1-hot) + broadcast hnb row; writes contiguous 1KB per slice.
    {
        const float* hr = hp  + ((size_t)(b*NJK + jk0 + lr))*HID;
        const float* nr = hnb + ((size_t)(b*NN + i0 + w))*HID;
        #pragma unroll 4
        for (int ks = 0; ks < 16; ++ks) {
            int k0 = ks*32 + lg*8;
            float4 p0 = *(const float4*)(hr + k0), p1 = *(const float4*)(hr + k0 + 4);
            float4 n0 = *(const float4*)(nr + k0), n1 = *(const float4*)(nr + k0 + 4);
            short8 u;
            u[0] = (short)f2bf(fmaxf(p0.x + n0.x, 0.f));
            u[1] = (short)f2bf(fmaxf(p0.y + n0.y, 0.f));
            u[2] = (short)f2bf(fmaxf(p0.z + n0.z, 0.f));
            u[3] = (short)f2bf(fmaxf(p0.w + n0.w, 0.f));
            u[4] = (short)f2bf(fmaxf(p1.x + n1.x, 0.f));
            u[5] = (short)f2bf(fmaxf(p1.y + n1.y, 0.f));
            u[6] = (short)f2bf(fmaxf(p1.z + n1.z, 0.f));
            u[7] = (short)f2bf(fmaxf(p1.w + n1.w, 0.f));
            *(short8*)(h1c + ((ks*8 + w) << 10) + l*16) = u;
        }
    }
    __syncthreads();

    floatx4 acc[8][4];
    #pragma unroll
    for (int mi = 0; mi < 8; ++mi)
        #pragma unroll
        for (int tn = 0; tn < 4; ++tn)
            acc[mi][tn] = (floatx4){0.f, 0.f, 0.f, 0.f};

    #pragma unroll 1
    for (int ks = 0; ks < 16; ++ks) {
        short8 bnxt[4];
        int ksn = (ks + 1) & 15;
        #pragma unroll
        for (int tn = 0; tn < 4; ++tn)
            bnxt[tn] = *(const short8*)(bbase + ((tn*16 + ksn) << 9));
        short8 av[8];
        #pragma unroll
        for (int mi = 0; mi < 8; ++mi)
            av[mi] = *(const short8*)(h1c + ((ks*8 + mi) << 10) + l*16);
        #pragma unroll
        for (int mi = 0; mi < 8; ++mi)
            #pragma unroll
            for (int tn = 0; tn < 4; ++tn)
                acc[mi][tn] = __builtin_amdgcn_mfma_f32_16x16x32_bf16(av[mi], bcur[tn], acc[mi][tn], 0, 0, 0);
        #pragma unroll
        for (int tn = 0; tn < 4; ++tn) bcur[tn] = bnxt[tn];
    }

    // ---- epilogue: v = relu(acc+b2)@W3, reduce over col-waves, sigmoid ----
    float b2v[4], w3v[4];
    #pragma unroll
    for (int tn = 0; tn < 4; ++tn) {
        int col = w*64 + tn*16 + lr;
        b2v[tn] = b2[col];
        w3v[tn] = W3[col];
    }
    #pragma unroll
    for (int mi = 0; mi < 8; ++mi) {
        #pragma unroll
        for (int q = 0; q < 4; ++q) {
            float s = 0.f;
            #pragma unroll
            for (int tn = 0; tn < 4; ++tn)
                s += fmaxf(acc[mi][tn][q] + b2v[tn], 0.f) * w3v[tn];
            s += __shfl_xor(s, 1);
            s += __shfl_xor(s, 2);
            s += __shfl_xor(s, 4);
            s += __shfl_xor(s, 8);
            if (lr == 0) red[w][mi*16 + lg*4 + q] = s;
        }
    }
    __syncthreads();
    if (t < 128) {
        float v = b3[0];
        #pragma unroll
        for (int c = 0; c < 8; ++c) v += red[c][t];
        float z = scale[0]*v + bias[0];
        int il = t >> 4, jl = t & 15;
        out[(size_t)b*MROW + (size_t)(i0 + il)*NJK + jk0 + jl] =
            1.0f / (1.0f + expf(-z));
    }
}

extern "C" void kernel_launch(void* const* d_in, const int* in_sizes, int n_in,
                              void* d_out, int out_size, void* d_ws, size_t ws_size,
                              hipStream_t stream) {
    const float* node  = (const float*)d_in[0];
    const float* pair  = (const float*)d_in[1];
    const float* W1n   = (const float*)d_in[2];
    const float* W1p   = (const float*)d_in[3];
    const float* b1    = (const float*)d_in[4];
    const float* W2    = (const float*)d_in[5];
    const float* b2    = (const float*)d_in[6];
    const float* W3    = (const float*)d_in[7];
    const float* b3    = (const float*)d_in[8];
    const float* scale = (const float*)d_in[9];
    const float* bias  = (const float*)d_in[10];
    float* out = (float*)d_out;

    float* hp  = (float*)d_ws;                                  // 3200*512 f32
    float* hnb = hp + (size_t)BB*NJK*HID;                       // 80*512 f32
    unsigned short* w2f = (unsigned short*)(hnb + BB*NN*HID);   // 512*512 bf16

    hipLaunchKernelGGL(prep_kernel, dim3(426), dim3(256), 0, stream,
                       node, pair, W1n, W1p, b1, W2, hp, hnb, w2f);
    hipLaunchKernelGGL(main_kernel, dim3(1000), dim3(512), 0, stream,
                       hp, hnb, w2f, b2, W3, b3, scale, bias, out);
}

// Round 8
// 181.032 us; speedup vs baseline: 1.2852x; 1.1046x over previous
//
#include <hip/hip_runtime.h>
#include <math.h>

#define BB 2
#define DD 8
#define NN 40
#define HH 128
#define HID 512
#define NJK 1600            // NN*NN
#define MROW 64000          // NN*NJK rows per batch

typedef __attribute__((ext_vector_type(8))) short short8;
typedef __attribute__((ext_vector_type(4))) float floatx4;

static __device__ __forceinline__ unsigned short f2bf(float x) {
    unsigned int b = __float_as_uint(x);
    b += 0x7fffu + ((b >> 16) & 1u);
    return (unsigned short)(b >> 16);
}

// Fused prep, 426 blocks x 256 (known-good since R5):
//  bid [0,400)   : hp rows bid*8..+7      (max_d(pair) @ W1p, fp32)
//  bid [400,410) : hnb rows (bid-400)*8..+7  (max_d(node) @ W1n + b1)
//  bid [410,426) : w2f — W2 k-slice ks=bid-410 packed bf16 in MFMA-frag order:
//                  frag f = cf*16+ks at w2f+f*512; lane l: n=cf*16+(l&15),
//                  k = ks*32+(l>>4)*8 .. +7
__global__ __launch_bounds__(256) void prep_kernel(
        const float* __restrict__ node, const float* __restrict__ pair,
        const float* __restrict__ W1n, const float* __restrict__ W1p,
        const float* __restrict__ b1, const float* __restrict__ W2,
        float* __restrict__ hp, float* __restrict__ hnb,
        unsigned short* __restrict__ w2f) {
    __shared__ float smem[32 * 513];
    const int bid = blockIdx.x;
    const int t = threadIdx.x;

    if (bid < 400) {                                   // ---- hp ----
        float (*pf)[HH] = (float (*)[HH])smem;
        const int rowbase = bid * 8;
        #pragma unroll
        for (int e = t; e < 8*HH; e += 256) {
            int r8 = e >> 7, c = e & 127;
            int grow = rowbase + r8;
            int b = grow / NJK, jk = grow - b*NJK;
            float m = -INFINITY;
            #pragma unroll
            for (int d = 0; d < DD; ++d)
                m = fmaxf(m, pair[((size_t)((b*DD + d)*NJK + jk))*HH + c]);
            pf[r8][c] = m;
        }
        __syncthreads();
        const int rg = t >> 7, c4 = (t & 127) * 4;
        float4 acc[4];
        #pragma unroll
        for (int r = 0; r < 4; ++r) acc[r] = make_float4(0.f,0.f,0.f,0.f);
        #pragma unroll 4
        for (int h = 0; h < HH; ++h) {
            float4 wv = *(const float4*)&W1p[h*HID + c4];
            #pragma unroll
            for (int r = 0; r < 4; ++r) {
                float pv = pf[rg*4 + r][h];
                acc[r].x = fmaf(pv, wv.x, acc[r].x);
                acc[r].y = fmaf(pv, wv.y, acc[r].y);
                acc[r].z = fmaf(pv, wv.z, acc[r].z);
                acc[r].w = fmaf(pv, wv.w, acc[r].w);
            }
        }
        #pragma unroll
        for (int r = 0; r < 4; ++r)
            *(float4*)&hp[(size_t)(rowbase + rg*4 + r)*HID + c4] = acc[r];
    } else if (bid < 410) {                            // ---- hnb ----
        float (*nf)[HH] = (float (*)[HH])smem;
        const int rowbase = (bid - 400) * 8;
        #pragma unroll
        for (int e = t; e < 8*HH; e += 256) {
            int r8 = e >> 7, c = e & 127;
            int grow = rowbase + r8;
            int b = grow / NN, i = grow - b*NN;
            float m = -INFINITY;
            #pragma unroll
            for (int d = 0; d < DD; ++d)
                m = fmaxf(m, node[((size_t)((b*DD + d)*NN + i))*HH + c]);
            nf[r8][c] = m;
        }
        __syncthreads();
        const int rg = t >> 7, c4 = (t & 127) * 4;
        float4 acc[4];
        #pragma unroll
        for (int r = 0; r < 4; ++r) acc[r] = make_float4(0.f,0.f,0.f,0.f);
        #pragma unroll 4
        for (int h = 0; h < HH; ++h) {
            float4 wv = *(const float4*)&W1n[h*HID + c4];
            #pragma unroll
            for (int r = 0; r < 4; ++r) {
                float nv = nf[rg*4 + r][h];
                acc[r].x = fmaf(nv, wv.x, acc[r].x);
                acc[r].y = fmaf(nv, wv.y, acc[r].y);
                acc[r].z = fmaf(nv, wv.z, acc[r].z);
                acc[r].w = fmaf(nv, wv.w, acc[r].w);
            }
        }
        float4 b1v = *(const float4*)&b1[c4];
        #pragma unroll
        for (int r = 0; r < 4; ++r) {
            float4 o = make_float4(acc[r].x + b1v.x, acc[r].y + b1v.y,
                                   acc[r].z + b1v.z, acc[r].w + b1v.w);
            *(float4*)&hnb[(size_t)(rowbase + rg*4 + r)*HID + c4] = o;
        }
    } else {                                           // ---- w2f ----
        const int ks = bid - 410;
        for (int e = t; e < 32*HID; e += 256) {
            int r = e >> 9, c = e & 511;
            smem[r*513 + c] = W2[(size_t)(ks*32 + r)*HID + c];
        }
        __syncthreads();
        const int w = t >> 6, l = t & 63;
        const int lr = l & 15, lg = l >> 4;
        #pragma unroll
        for (int f = 0; f < 8; ++f) {
            int cf = w*8 + f;
            short8 u;
            #pragma unroll
            for (int kk = 0; kk < 8; ++kk)
                u[kk] = (short)f2bf(smem[(lg*8 + kk)*513 + cf*16 + lr]);
            *(short8*)(w2f + (size_t)(cf*16 + ks)*512 + l*8) = u;
        }
    }
}

// Main: 2000 blocks x 512. Tile = 4 i x 16 jk = 64 rows x 512 cols.
// LDS 66KB -> 2 blocks/CU co-resident: stage(VALU/L1) of one block overlaps
// k-loop(MFMA) of the other (m114 co-scheduling). Frag-packed h1 LDS:
// frag (ks,mi) contiguous 1KB; all LDS b128 accesses are lane-contiguous
// (l*16) on both write and read -> zero bank conflicts (R7-proven).
// 8 col-waves x 64 cols, acc[4][4]; B 1-ahead register prefetch from w2f.
__global__ __launch_bounds__(512, 4) void main_kernel(
        const float* __restrict__ hp, const float* __restrict__ hnb,
        const unsigned short* __restrict__ w2f,
        const float* __restrict__ b2, const float* __restrict__ W3,
        const float* __restrict__ b3, const float* __restrict__ scale,
        const float* __restrict__ bias, float* __restrict__ out) {
    __shared__ __align__(16) unsigned short h1s[64 * HID];   // 64 KiB frag-packed
    __shared__ float red[8][64];                             // 2 KiB

    const int bid  = blockIdx.x;                       // 0..1999
    const int bid8 = (bid & 7)*250 + (bid >> 3);       // bijective XCD swizzle
    const int b    = bid8 / 1000;
    const int rem  = bid8 % 1000;
    const int i0   = (rem / 100) * 4;
    const int jk0  = (rem % 100) * 16;
    const int t    = threadIdx.x;
    char* h1c = (char*)h1s;

    const int w  = t >> 6, l = t & 63;
    const int lr = l & 15, lg = l >> 4;

    // hoist first B-frag loads (global, independent) to overlap the stage
    const unsigned short* bbase = w2f + (size_t)w*32768 + l*8;
    short8 bcur[4];
    #pragma unroll
    for (int tn = 0; tn < 4; ++tn)
        bcur[tn] = *(const short8*)(bbase + ((tn*16) << 9));

    // ---- stage h1 = relu(hnb[i0+mi] + hp[jk0+(l&15)]) into frag-packed LDS ----
    // wave w stages 8 frags: ks = w*2 + (j>>2), mi = j&3. Lane-contiguous writes.
    {
        const float* hrow = hp + ((size_t)(b*NJK + jk0 + lr))*HID;
        const float* nbase = hnb + ((size_t)(b*NN + i0))*HID;
        #pragma unroll
        for (int j = 0; j < 8; ++j) {
            int ks = w*2 + (j >> 2), mi = j & 3;
            int k0 = ks*32 + lg*8;
            const float* hr = hrow + k0;
            const float* nr = nbase + mi*HID + k0;
            float4 p0 = *(const float4*)hr, p1 = *(const float4*)(hr + 4);
            float4 n0 = *(const float4*)nr, n1 = *(const float4*)(nr + 4);
            short8 u;
            u[0] = (short)f2bf(fmaxf(p0.x + n0.x, 0.f));
            u[1] = (short)f2bf(fmaxf(p0.y + n0.y, 0.f));
            u[2] = (short)f2bf(fmaxf(p0.z + n0.z, 0.f));
            u[3] = (short)f2bf(fmaxf(p0.w + n0.w, 0.f));
            u[4] = (short)f2bf(fmaxf(p1.x + n1.x, 0.f));
            u[5] = (short)f2bf(fmaxf(p1.y + n1.y, 0.f));
            u[6] = (short)f2bf(fmaxf(p1.z + n1.z, 0.f));
            u[7] = (short)f2bf(fmaxf(p1.w + n1.w, 0.f));
            *(short8*)(h1c + ((ks*4 + mi) << 10) + l*16) = u;
        }
    }
    __syncthreads();

    floatx4 acc[4][4];
    #pragma unroll
    for (int mi = 0; mi < 4; ++mi)
        #pragma unroll
        for (int tn = 0; tn < 4; ++tn)
            acc[mi][tn] = (floatx4){0.f, 0.f, 0.f, 0.f};

    #pragma unroll 1
    for (int ks = 0; ks < 16; ++ks) {
        short8 bnxt[4];
        int ksn = (ks + 1) & 15;
        #pragma unroll
        for (int tn = 0; tn < 4; ++tn)
            bnxt[tn] = *(const short8*)(bbase + ((tn*16 + ksn) << 9));
        short8 av[4];
        #pragma unroll
        for (int mi = 0; mi < 4; ++mi)
            av[mi] = *(const short8*)(h1c + ((ks*4 + mi) << 10) + l*16);
        __builtin_amdgcn_s_setprio(1);
        #pragma unroll
        for (int mi = 0; mi < 4; ++mi)
            #pragma unroll
            for (int tn = 0; tn < 4; ++tn)
                acc[mi][tn] = __builtin_amdgcn_mfma_f32_16x16x32_bf16(av[mi], bcur[tn], acc[mi][tn], 0, 0, 0);
        __builtin_amdgcn_s_setprio(0);
        #pragma unroll
        for (int tn = 0; tn < 4; ++tn) bcur[tn] = bnxt[tn];
    }

    // ---- epilogue: v = relu(acc+b2)@W3, reduce over col-waves, sigmoid ----
    float b2v[4], w3v[4];
    #pragma unroll
    for (int tn = 0; tn < 4; ++tn) {
        int col = w*64 + tn*16 + lr;
        b2v[tn] = b2[col];
        w3v[tn] = W3[col];
    }
    #pragma unroll
    for (int mi = 0; mi < 4; ++mi) {
        #pragma unroll
        for (int q = 0; q < 4; ++q) {
            float s = 0.f;
            #pragma unroll
            for (int tn = 0; tn < 4; ++tn)
                s += fmaxf(acc[mi][tn][q] + b2v[tn], 0.f) * w3v[tn];
            s += __shfl_xor(s, 1);
            s += __shfl_xor(s, 2);
            s += __shfl_xor(s, 4);
            s += __shfl_xor(s, 8);
            if (lr == 0) red[w][mi*16 + lg*4 + q] = s;
        }
    }
    __syncthreads();
    if (t < 64) {
        float v = b3[0];
        #pragma unroll
        for (int c = 0; c < 8; ++c) v += red[c][t];
        float z = scale[0]*v + bias[0];
        int il = t >> 4, jl = t & 15;
        out[(size_t)b*MROW + (size_t)(i0 + il)*NJK + jk0 + jl] =
            1.0f / (1.0f + expf(-z));
    }
}

extern "C" void kernel_launch(void* const* d_in, const int* in_sizes, int n_in,
                              void* d_out, int out_size, void* d_ws, size_t ws_size,
                              hipStream_t stream) {
    const float* node  = (const float*)d_in[0];
    const float* pair  = (const float*)d_in[1];
    const float* W1n   = (const float*)d_in[2];
    const float* W1p   = (const float*)d_in[3];
    const float* b1    = (const float*)d_in[4];
    const float* W2    = (const float*)d_in[5];
    const float* b2    = (const float*)d_in[6];
    const float* W3    = (const float*)d_in[7];
    const float* b3    = (const float*)d_in[8];
    const float* scale = (const float*)d_in[9];
    const float* bias  = (const float*)d_in[10];
    float* out = (float*)d_out;

    float* hp  = (float*)d_ws;                                  // 3200*512 f32
    float* hnb = hp + (size_t)BB*NJK*HID;                       // 80*512 f32
    unsigned short* w2f = (unsigned short*)(hnb + BB*NN*HID);   // 512*512 bf16

    hipLaunchKernelGGL(prep_kernel, dim3(426), dim3(256), 0, stream,
                       node, pair, W1n, W1p, b1, W2, hp, hnb, w2f);
    hipLaunchKernelGGL(main_kernel, dim3(2000), dim3(512), 0, stream,
                       hp, hnb, w2f, b2, W3, b3, scale, bias, out);
}